// Round 4
// baseline (714.440 us; speedup 1.0000x reference)
//
#include <hip/hip_runtime.h>

// GraphConvolution: out = segment_sum(edge_val * (x@W)[edge_col], edge_row) + b
// M=100000 nodes, K=256 in_feats, N=128 out_feats, E=1.6M edges. fp32 in/out.
//
// R4: replace global counting-sort scatter (fill_sorted: 100MB WRITE, 8x line
// amp, 127us) with two-level bucket sort: coarse append (write amp ~1) +
// per-bucket LDS sort (contiguous output window). Also folds the global
// hist+3-kernel-scan pipeline into the per-bucket pass.

#define K_FEATS 256
#define N_FEATS 128
#define BSHIFT 7                 // 128 rows per bucket
#define BROWS 128
#define BCAP 3072                // mean 2048, +22 sigma

typedef __attribute__((ext_vector_type(8))) short short8;
typedef __attribute__((ext_vector_type(4))) float float4v;

__device__ __forceinline__ unsigned short f2bf(float f) {
    unsigned int u = __float_as_uint(f);
    unsigned int r = u + 0x7FFF + ((u >> 16) & 1);   // round-to-nearest-even
    return (unsigned short)(r >> 16);
}

// ---------------- prep: Wt[n][k] bf16 from w[k][n] fp32 ----------------
__global__ __launch_bounds__(256) void prep_w(const float* __restrict__ w,
                                              unsigned short* __restrict__ wt) {
    int n = blockIdx.x;
    int k = threadIdx.x;
    wt[n * K_FEATS + k] = f2bf(w[k * N_FEATS + n]);
}

// ---------------- GEMM: sup(bf16) = x @ W via MFMA ----------------
__global__ __launch_bounds__(256) void gcn_gemm_mfma(const float* __restrict__ x,
                                                     const unsigned short* __restrict__ wt,
                                                     unsigned short* __restrict__ sup, int M) {
    __shared__ __align__(16) unsigned short As[128 * 40];

    const int tid  = threadIdx.x;
    const int wv   = tid >> 6;
    const int lane = tid & 63;
    const int l15  = lane & 15;
    const int quad = lane >> 4;
    const int row0 = blockIdx.x * 128;

    float4v acc[2][8];
#pragma unroll
    for (int mt = 0; mt < 2; mt++)
#pragma unroll
        for (int nt = 0; nt < 8; nt++) acc[mt][nt] = (float4v)(0.f);

    for (int k0 = 0; k0 < K_FEATS; k0 += 32) {
#pragma unroll
        for (int l = 0; l < 4; l++) {
            int f   = tid + l * 256;
            int r   = f >> 3;
            int k4  = f & 7;
            int grow = row0 + r;
            float4 v = make_float4(0.f, 0.f, 0.f, 0.f);
            if (grow < M) v = *(const float4*)(x + (long)grow * K_FEATS + k0 + k4 * 4);
            unsigned int p0 = (unsigned int)f2bf(v.x) | ((unsigned int)f2bf(v.y) << 16);
            unsigned int p1 = (unsigned int)f2bf(v.z) | ((unsigned int)f2bf(v.w) << 16);
            *(uint2*)(&As[r * 40 + k4 * 4]) = make_uint2(p0, p1);
        }
        __syncthreads();

        short8 afrag[2];
#pragma unroll
        for (int mt = 0; mt < 2; mt++) {
            afrag[mt] = *(const short8*)(&As[(wv * 32 + mt * 16 + l15) * 40 + quad * 8]);
        }
        short8 bfrag[8];
#pragma unroll
        for (int nt = 0; nt < 8; nt++) {
            bfrag[nt] = *(const short8*)(wt + (nt * 16 + l15) * K_FEATS + k0 + quad * 8);
        }
#pragma unroll
        for (int mt = 0; mt < 2; mt++)
#pragma unroll
            for (int nt = 0; nt < 8; nt++)
                acc[mt][nt] = __builtin_amdgcn_mfma_f32_16x16x32_bf16(
                    afrag[mt], bfrag[nt], acc[mt][nt], 0, 0, 0);
        __syncthreads();
    }

#pragma unroll
    for (int mt = 0; mt < 2; mt++) {
#pragma unroll
        for (int reg = 0; reg < 4; reg++) {
            int grow = row0 + wv * 32 + mt * 16 + quad * 4 + reg;
            if (grow < M) {
#pragma unroll
                for (int nt = 0; nt < 8; nt++) {
                    sup[(long)grow * N_FEATS + nt * 16 + l15] = f2bf(acc[mt][nt][reg]);
                }
            }
        }
    }
}

// ---------------- bucket sort ----------------
__global__ __launch_bounds__(256) void zero_ints(int* __restrict__ p, int n) {
    int i = blockIdx.x * 256 + threadIdx.x;
    if (i < n) p[i] = 0;
}

// append edges to coarse buckets (row>>7); pack (rowlow<<17 | col, valbits)
__global__ __launch_bounds__(256) void bucket_scatter(const int* __restrict__ erow,
                                                      const int* __restrict__ ecol,
                                                      const float* __restrict__ eval_,
                                                      int* __restrict__ bcur,
                                                      int2* __restrict__ tmp, int E) {
    int e = blockIdx.x * 256 + threadIdx.x;
    if (e >= E) return;
    int r = erow[e];
    int c = ecol[e];
    int b = r >> BSHIFT;
    int p = atomicAdd(&bcur[b], 1);
    if (p < BCAP)
        tmp[(long)b * BCAP + p] = make_int2(((r & (BROWS - 1)) << 17) | c,
                                            __float_as_int(eval_[e]));
}

// exclusive scan of bucket counts (NB <= 1024), single block; off0[M] = total
__global__ __launch_bounds__(1024) void bucket_scan(const int* __restrict__ bcnt,
                                                    int* __restrict__ bbase,
                                                    int* __restrict__ off0,
                                                    int NB, int M) {
    __shared__ int sm[1024];
    int t = threadIdx.x;
    int v = 0;
    if (t < NB) { v = bcnt[t]; if (v > BCAP) v = BCAP; }
    sm[t] = v;
    __syncthreads();
#pragma unroll
    for (int s = 1; s < 1024; s <<= 1) {
        int a = (t >= s) ? sm[t - s] : 0;
        __syncthreads();
        sm[t] += a;
        __syncthreads();
    }
    if (t < NB) bbase[t] = sm[t] - v;
    if (t == 1023) off0[M] = sm[1023];
}

// one block per bucket: LDS histogram + scan of its 128 rows -> off0,
// then place edges into contiguous sorted window of sedge.
__global__ __launch_bounds__(256) void bucket_to_sorted(const int* __restrict__ bcnt,
                                                        const int* __restrict__ bbase,
                                                        const int2* __restrict__ tmp,
                                                        int* __restrict__ off0,
                                                        int2* __restrict__ sedge, int M) {
    __shared__ int hist[BROWS];
    __shared__ int cur[BROWS];
    const int b   = blockIdx.x;
    const int tid = threadIdx.x;
    const int row0 = b << BSHIFT;

    if (tid < BROWS) hist[tid] = 0;
    __syncthreads();

    int cnt = bcnt[b];
    if (cnt > BCAP) cnt = BCAP;
    const int2* t = tmp + (long)b * BCAP;

    for (int i = tid; i < cnt; i += 256)
        atomicAdd(&hist[(unsigned)t[i].x >> 17], 1);
    __syncthreads();

    if (tid < BROWS) cur[tid] = hist[tid];
    __syncthreads();
#pragma unroll
    for (int s = 1; s < BROWS; s <<= 1) {
        int v = 0;
        if (tid >= s && tid < BROWS) v = cur[tid - s];
        __syncthreads();
        if (tid < BROWS) cur[tid] += v;
        __syncthreads();
    }

    const int base = bbase[b];
    if (tid < BROWS) {
        int start = base + cur[tid] - hist[tid];   // exclusive
        cur[tid] = start;
        if (row0 + tid < M) off0[row0 + tid] = start;
    }
    __syncthreads();

    for (int i = tid; i < cnt; i += 256) {
        int2 e = t[i];
        int rl = (unsigned)e.x >> 17;
        int p = atomicAdd(&cur[rl], 1);
        sedge[p] = make_int2(e.x & 0x1FFFF, e.y);
    }
}

// ---------------- SpMM: wave per row, bf16 sup gather, no atomics ----------------
__global__ __launch_bounds__(256) void gcn_spmm(const int* __restrict__ off0,
                                                const int2* __restrict__ sedge,
                                                const unsigned short* __restrict__ sup,
                                                const float* __restrict__ b,
                                                float* __restrict__ out, int M) {
    int row  = blockIdx.x * 4 + (threadIdx.x >> 6);
    int lane = threadIdx.x & 63;
    if (row >= M) return;
    int s = off0[row], e = off0[row + 1];
    const unsigned int* sup32 = (const unsigned int*)sup;   // 2 bf16 per uint
    float2 acc = make_float2(0.f, 0.f);
    int i = s;
    for (; i + 1 < e; i += 2) {
        int2 e0 = sedge[i];
        int2 e1 = sedge[i + 1];
        float v0 = __int_as_float(e0.y);
        float v1 = __int_as_float(e1.y);
        unsigned int u0 = sup32[(long)e0.x * 64 + lane];
        unsigned int u1 = sup32[(long)e1.x * 64 + lane];
        acc.x += v0 * __uint_as_float(u0 << 16);
        acc.y += v0 * __uint_as_float(u0 & 0xFFFF0000u);
        acc.x += v1 * __uint_as_float(u1 << 16);
        acc.y += v1 * __uint_as_float(u1 & 0xFFFF0000u);
    }
    if (i < e) {
        int2 e0 = sedge[i];
        float v0 = __int_as_float(e0.y);
        unsigned int u0 = sup32[(long)e0.x * 64 + lane];
        acc.x += v0 * __uint_as_float(u0 << 16);
        acc.y += v0 * __uint_as_float(u0 & 0xFFFF0000u);
    }
    float2 bb = ((const float2*)b)[lane];
    ((float2*)out)[(long)row * 64 + lane] = make_float2(acc.x + bb.x, acc.y + bb.y);
}

extern "C" void kernel_launch(void* const* d_in, const int* in_sizes, int n_in,
                              void* d_out, int out_size, void* d_ws, size_t ws_size,
                              hipStream_t stream) {
    const float* x     = (const float*)d_in[0];
    const int*   erow  = (const int*)d_in[1];
    const int*   ecol  = (const int*)d_in[2];
    const float* eval_ = (const float*)d_in[3];
    const float* w     = (const float*)d_in[4];
    const float* b     = (const float*)d_in[5];
    float* out = (float*)d_out;

    const int M  = in_sizes[0] / K_FEATS;      // 100000
    const int E  = in_sizes[1];                // 1600000
    const int NB = (M + BROWS - 1) >> BSHIFT;  // 782

    // workspace layout (16B aligned)
    size_t o_sup   = 0;                                               // bf16 sup
    size_t o_wt    = o_sup   + (((size_t)M * N_FEATS * 2 + 15) & ~15ul);
    size_t o_off0  = o_wt    + (size_t)K_FEATS * N_FEATS * 2;
    size_t o_bcur  = o_off0  + (((size_t)(M + 1) * 4 + 15) & ~15ul);
    size_t o_bbase = o_bcur  + (((size_t)NB * 4 + 15) & ~15ul);
    size_t o_tmp   = o_bbase + (((size_t)NB * 4 + 15) & ~15ul);
    size_t o_edge  = o_tmp   + ((size_t)NB * BCAP * 8);
    // total ~= 25.6 + 19.2 + 12.8 MB + small  ~ 58 MB

    unsigned short* sup   = (unsigned short*)((char*)d_ws + o_sup);
    unsigned short* wt    = (unsigned short*)((char*)d_ws + o_wt);
    int*            off0  = (int*)((char*)d_ws + o_off0);
    int*            bcur  = (int*)((char*)d_ws + o_bcur);
    int*            bbase = (int*)((char*)d_ws + o_bbase);
    int2*           tmp   = (int2*)((char*)d_ws + o_tmp);
    int2*           sedge = (int2*)((char*)d_ws + o_edge);

    // dense path: W -> Wt bf16, sup = bf16(x @ W)
    prep_w<<<N_FEATS, 256, 0, stream>>>(w, wt);
    gcn_gemm_mfma<<<(M + 127) / 128, 256, 0, stream>>>(x, wt, sup, M);

    // sparse path: two-level bucket sort by destination row
    zero_ints<<<(NB + 255) / 256, 256, 0, stream>>>(bcur, NB);
    bucket_scatter<<<(E + 255) / 256, 256, 0, stream>>>(erow, ecol, eval_, bcur, tmp, E);
    bucket_scan<<<1, 1024, 0, stream>>>(bcur, bbase, off0, NB, M);
    bucket_to_sorted<<<NB, 256, 0, stream>>>(bcur, bbase, tmp, off0, sedge, M);

    // out[row] = sum(val * sup[col]) + b
    gcn_spmm<<<(M + 3) / 4, 256, 0, stream>>>(off0, sedge, sup, b, out, M);
}

// Round 5
// 390.297 us; speedup vs baseline: 1.8305x; 1.8305x over previous
//
#include <hip/hip_runtime.h>

// GraphConvolution: out = segment_sum(edge_val * (x@W)[edge_col], edge_row) + b
// M=100000 nodes, K=256 in_feats, N=128 out_feats, E=1.6M edges. fp32 in/out.
//
// R5: R4's bucket_scatter died on same-address atomic serialization
// (1.6M atomics / 782 cursors = 2046-deep chains @ ~185ns = 379us).
// Fix: wg_partition does LDS histogram per 8192-edge chunk, then ONE global
// atomicAdd per (WG,bucket) reservation (chain depth 196), then writes edges
// in ~84B runs (write amp ~1.4 vs R2 fill_sorted's 8x).

#define K_FEATS 256
#define N_FEATS 128
#define BSHIFT 7                 // 128 rows per bucket
#define BROWS 128
#define BCAP 3072                // mean 2048, +22 sigma
#define CHUNK 8192
#define EPT 32                   // edges per thread (256 threads)

typedef __attribute__((ext_vector_type(8))) short short8;
typedef __attribute__((ext_vector_type(4))) float float4v;

__device__ __forceinline__ unsigned short f2bf(float f) {
    unsigned int u = __float_as_uint(f);
    unsigned int r = u + 0x7FFF + ((u >> 16) & 1);   // round-to-nearest-even
    return (unsigned short)(r >> 16);
}

// ---------------- prep: Wt[n][k] bf16 from w[k][n] fp32 ----------------
__global__ __launch_bounds__(256) void prep_w(const float* __restrict__ w,
                                              unsigned short* __restrict__ wt) {
    int n = blockIdx.x;
    int k = threadIdx.x;
    wt[n * K_FEATS + k] = f2bf(w[k * N_FEATS + n]);
}

// ---------------- GEMM: sup(bf16) = x @ W via MFMA ----------------
__global__ __launch_bounds__(256) void gcn_gemm_mfma(const float* __restrict__ x,
                                                     const unsigned short* __restrict__ wt,
                                                     unsigned short* __restrict__ sup, int M) {
    __shared__ __align__(16) unsigned short As[128 * 40];

    const int tid  = threadIdx.x;
    const int wv   = tid >> 6;
    const int lane = tid & 63;
    const int l15  = lane & 15;
    const int quad = lane >> 4;
    const int row0 = blockIdx.x * 128;

    float4v acc[2][8];
#pragma unroll
    for (int mt = 0; mt < 2; mt++)
#pragma unroll
        for (int nt = 0; nt < 8; nt++) acc[mt][nt] = (float4v)(0.f);

    for (int k0 = 0; k0 < K_FEATS; k0 += 32) {
#pragma unroll
        for (int l = 0; l < 4; l++) {
            int f   = tid + l * 256;
            int r   = f >> 3;
            int k4  = f & 7;
            int grow = row0 + r;
            float4 v = make_float4(0.f, 0.f, 0.f, 0.f);
            if (grow < M) v = *(const float4*)(x + (long)grow * K_FEATS + k0 + k4 * 4);
            unsigned int p0 = (unsigned int)f2bf(v.x) | ((unsigned int)f2bf(v.y) << 16);
            unsigned int p1 = (unsigned int)f2bf(v.z) | ((unsigned int)f2bf(v.w) << 16);
            *(uint2*)(&As[r * 40 + k4 * 4]) = make_uint2(p0, p1);
        }
        __syncthreads();

        short8 afrag[2];
#pragma unroll
        for (int mt = 0; mt < 2; mt++) {
            afrag[mt] = *(const short8*)(&As[(wv * 32 + mt * 16 + l15) * 40 + quad * 8]);
        }
        short8 bfrag[8];
#pragma unroll
        for (int nt = 0; nt < 8; nt++) {
            bfrag[nt] = *(const short8*)(wt + (nt * 16 + l15) * K_FEATS + k0 + quad * 8);
        }
#pragma unroll
        for (int mt = 0; mt < 2; mt++)
#pragma unroll
            for (int nt = 0; nt < 8; nt++)
                acc[mt][nt] = __builtin_amdgcn_mfma_f32_16x16x32_bf16(
                    afrag[mt], bfrag[nt], acc[mt][nt], 0, 0, 0);
        __syncthreads();
    }

#pragma unroll
    for (int mt = 0; mt < 2; mt++) {
#pragma unroll
        for (int reg = 0; reg < 4; reg++) {
            int grow = row0 + wv * 32 + mt * 16 + quad * 4 + reg;
            if (grow < M) {
#pragma unroll
                for (int nt = 0; nt < 8; nt++) {
                    sup[(long)grow * N_FEATS + nt * 16 + l15] = f2bf(acc[mt][nt][reg]);
                }
            }
        }
    }
}

// ---------------- bucket sort ----------------
__global__ __launch_bounds__(256) void zero_ints(int* __restrict__ p, int n) {
    int i = blockIdx.x * 256 + threadIdx.x;
    if (i < n) p[i] = 0;
}

// Phase 1: per-chunk LDS histogram -> one reservation atomic per (WG,bucket)
// -> write edges to reserved runs inside bucket-strided tmp regions.
__global__ __launch_bounds__(256) void wg_partition(const int* __restrict__ erow,
                                                    const int* __restrict__ ecol,
                                                    const float* __restrict__ eval_,
                                                    int* __restrict__ bcur,
                                                    int2* __restrict__ tmp, int E, int NB) {
    __shared__ int hist[1024];
    __shared__ int cur[1024];
    const int tid = threadIdx.x;
    const long e0 = (long)blockIdx.x * CHUNK;

    for (int i = tid; i < NB; i += 256) hist[i] = 0;
    __syncthreads();

    int rows[EPT];
#pragma unroll
    for (int i = 0; i < EPT; i++) {
        long e = e0 + tid + i * 256;
        int r = -1;
        if (e < E) {
            r = erow[e];
            atomicAdd(&hist[r >> BSHIFT], 1);
        }
        rows[i] = r;
    }
    __syncthreads();

    // one global reservation per touched bucket
    for (int i = tid; i < NB; i += 256) {
        int c = hist[i];
        cur[i] = c ? atomicAdd(&bcur[i], c) : 0;
    }
    __syncthreads();

    // place edges: LDS cursor gives offset within this WG's reserved run
#pragma unroll
    for (int i = 0; i < EPT; i++) {
        long e = e0 + tid + i * 256;
        if (e >= E) continue;
        int r = rows[i];
        int b = r >> BSHIFT;
        int p = atomicAdd(&cur[b], 1);
        if (p < BCAP)
            tmp[(long)b * BCAP + p] = make_int2(((r & (BROWS - 1)) << 17) | ecol[e],
                                                __float_as_int(eval_[e]));
    }
}

// exclusive scan of bucket counts (NB <= 1024), single block; off0[M] = total
__global__ __launch_bounds__(1024) void bucket_scan(const int* __restrict__ bcnt,
                                                    int* __restrict__ bbase,
                                                    int* __restrict__ off0,
                                                    int NB, int M) {
    __shared__ int sm[1024];
    int t = threadIdx.x;
    int v = 0;
    if (t < NB) { v = bcnt[t]; if (v > BCAP) v = BCAP; }
    sm[t] = v;
    __syncthreads();
#pragma unroll
    for (int s = 1; s < 1024; s <<= 1) {
        int a = (t >= s) ? sm[t - s] : 0;
        __syncthreads();
        sm[t] += a;
        __syncthreads();
    }
    if (t < NB) bbase[t] = sm[t] - v;
    if (t == 1023) off0[M] = sm[1023];
}

// one block per bucket: LDS histogram + scan of its 128 rows -> off0,
// then place edges into contiguous sorted window of sedge.
__global__ __launch_bounds__(256) void bucket_to_sorted(const int* __restrict__ bcnt,
                                                        const int* __restrict__ bbase,
                                                        const int2* __restrict__ tmp,
                                                        int* __restrict__ off0,
                                                        int2* __restrict__ sedge, int M) {
    __shared__ int hist[BROWS];
    __shared__ int cur[BROWS];
    const int b   = blockIdx.x;
    const int tid = threadIdx.x;
    const int row0 = b << BSHIFT;

    if (tid < BROWS) hist[tid] = 0;
    __syncthreads();

    int cnt = bcnt[b];
    if (cnt > BCAP) cnt = BCAP;
    const int2* t = tmp + (long)b * BCAP;

    for (int i = tid; i < cnt; i += 256)
        atomicAdd(&hist[(unsigned)t[i].x >> 17], 1);
    __syncthreads();

    if (tid < BROWS) cur[tid] = hist[tid];
    __syncthreads();
#pragma unroll
    for (int s = 1; s < BROWS; s <<= 1) {
        int v = 0;
        if (tid >= s && tid < BROWS) v = cur[tid - s];
        __syncthreads();
        if (tid < BROWS) cur[tid] += v;
        __syncthreads();
    }

    const int base = bbase[b];
    if (tid < BROWS) {
        int start = base + cur[tid] - hist[tid];   // exclusive
        cur[tid] = start;
        if (row0 + tid < M) off0[row0 + tid] = start;
    }
    __syncthreads();

    for (int i = tid; i < cnt; i += 256) {
        int2 e = t[i];
        int rl = (unsigned)e.x >> 17;
        int p = atomicAdd(&cur[rl], 1);
        sedge[p] = make_int2(e.x & 0x1FFFF, e.y);
    }
}

// ---------------- SpMM: wave per row, bf16 sup gather, no atomics ----------------
__global__ __launch_bounds__(256) void gcn_spmm(const int* __restrict__ off0,
                                                const int2* __restrict__ sedge,
                                                const unsigned short* __restrict__ sup,
                                                const float* __restrict__ b,
                                                float* __restrict__ out, int M) {
    int row  = blockIdx.x * 4 + (threadIdx.x >> 6);
    int lane = threadIdx.x & 63;
    if (row >= M) return;
    int s = off0[row], e = off0[row + 1];
    const unsigned int* sup32 = (const unsigned int*)sup;   // 2 bf16 per uint
    float2 acc = make_float2(0.f, 0.f);
    int i = s;
    for (; i + 1 < e; i += 2) {
        int2 e0 = sedge[i];
        int2 e1 = sedge[i + 1];
        float v0 = __int_as_float(e0.y);
        float v1 = __int_as_float(e1.y);
        unsigned int u0 = sup32[(long)e0.x * 64 + lane];
        unsigned int u1 = sup32[(long)e1.x * 64 + lane];
        acc.x += v0 * __uint_as_float(u0 << 16);
        acc.y += v0 * __uint_as_float(u0 & 0xFFFF0000u);
        acc.x += v1 * __uint_as_float(u1 << 16);
        acc.y += v1 * __uint_as_float(u1 & 0xFFFF0000u);
    }
    if (i < e) {
        int2 e0 = sedge[i];
        float v0 = __int_as_float(e0.y);
        unsigned int u0 = sup32[(long)e0.x * 64 + lane];
        acc.x += v0 * __uint_as_float(u0 << 16);
        acc.y += v0 * __uint_as_float(u0 & 0xFFFF0000u);
    }
    float2 bb = ((const float2*)b)[lane];
    ((float2*)out)[(long)row * 64 + lane] = make_float2(acc.x + bb.x, acc.y + bb.y);
}

extern "C" void kernel_launch(void* const* d_in, const int* in_sizes, int n_in,
                              void* d_out, int out_size, void* d_ws, size_t ws_size,
                              hipStream_t stream) {
    const float* x     = (const float*)d_in[0];
    const int*   erow  = (const int*)d_in[1];
    const int*   ecol  = (const int*)d_in[2];
    const float* eval_ = (const float*)d_in[3];
    const float* w     = (const float*)d_in[4];
    const float* b     = (const float*)d_in[5];
    float* out = (float*)d_out;

    const int M  = in_sizes[0] / K_FEATS;      // 100000
    const int E  = in_sizes[1];                // 1600000
    const int NB = (M + BROWS - 1) >> BSHIFT;  // 782

    // workspace layout (16B aligned)
    size_t o_sup   = 0;                                               // bf16 sup
    size_t o_wt    = o_sup   + (((size_t)M * N_FEATS * 2 + 15) & ~15ul);
    size_t o_off0  = o_wt    + (size_t)K_FEATS * N_FEATS * 2;
    size_t o_bcur  = o_off0  + (((size_t)(M + 1) * 4 + 15) & ~15ul);
    size_t o_bbase = o_bcur  + (((size_t)NB * 4 + 15) & ~15ul);
    size_t o_tmp   = o_bbase + (((size_t)NB * 4 + 15) & ~15ul);
    size_t o_edge  = o_tmp   + ((size_t)NB * BCAP * 8);

    unsigned short* sup   = (unsigned short*)((char*)d_ws + o_sup);
    unsigned short* wt    = (unsigned short*)((char*)d_ws + o_wt);
    int*            off0  = (int*)((char*)d_ws + o_off0);
    int*            bcur  = (int*)((char*)d_ws + o_bcur);
    int*            bbase = (int*)((char*)d_ws + o_bbase);
    int2*           tmp   = (int2*)((char*)d_ws + o_tmp);
    int2*           sedge = (int2*)((char*)d_ws + o_edge);

    // dense path: W -> Wt bf16, sup = bf16(x @ W)
    prep_w<<<N_FEATS, 256, 0, stream>>>(w, wt);
    gcn_gemm_mfma<<<(M + 127) / 128, 256, 0, stream>>>(x, wt, sup, M);

    // sparse path: reservation-based bucket partition, then per-bucket sort
    zero_ints<<<(NB + 255) / 256, 256, 0, stream>>>(bcur, NB);
    int nchunks = (E + CHUNK - 1) / CHUNK;     // 196
    wg_partition<<<nchunks, 256, 0, stream>>>(erow, ecol, eval_, bcur, tmp, E, NB);
    bucket_scan<<<1, 1024, 0, stream>>>(bcur, bbase, off0, NB, M);
    bucket_to_sorted<<<NB, 256, 0, stream>>>(bcur, bbase, tmp, off0, sedge, M);

    // out[row] = sum(val * sup[col]) + b
    gcn_spmm<<<(M + 3) / 4, 256, 0, stream>>>(off0, sedge, sup, b, out, M);
}